// Round 10
// baseline (199.315 us; speedup 1.0000x reference)
//
#include <hip/hip_runtime.h>
#include <math.h>

#define B_   8
#define CIN  768
#define HID  128
#define NA   36
#define PP   1024

typedef _Float16 f16;
typedef __attribute__((ext_vector_type(2))) _Float16 f16x2;
typedef __attribute__((ext_vector_type(4))) _Float16 f16x4;
typedef __attribute__((ext_vector_type(8))) _Float16 f16x8;
typedef __attribute__((ext_vector_type(4))) float f32x4;
typedef __attribute__((ext_vector_type(4))) unsigned short us4;

#define MFMA16(a, b, c) __builtin_amdgcn_mfma_f32_16x16x32_f16((a), (b), (c), 0, 0, 0)

__device__ inline f16x2 pkrtz(float a, float b) {
  union { __fp16 __attribute__((ext_vector_type(2))) r; f16x2 h; } u;
  u.r = __builtin_amdgcn_cvt_pkrtz(a, b);
  return u.h;
}

// RNE fp32x8 -> f16x8 (matches prep_k numerics from rounds 5-9)
__device__ inline f16x8 cvt8_rne(float4 lo, float4 hi) {
  f16x8 h;
  h[0] = (f16)lo.x; h[1] = (f16)lo.y; h[2] = (f16)lo.z; h[3] = (f16)lo.w;
  h[4] = (f16)hi.x; h[5] = (f16)hi.y; h[6] = (f16)hi.z; h[7] = (f16)hi.w;
  return h;
}

// ------------------------------------------------- rotation corner helper
__device__ inline void rot_corners(float ct, float st, int y, int x,
                                   float w[4], int p[4]) {
  float xn = (2.0f * x + 1.0f) * (1.0f / 32.0f) - 1.0f;
  float yn = (2.0f * y + 1.0f) * (1.0f / 32.0f) - 1.0f;
  float gx = ct * xn - st * yn;
  float gy = st * xn + ct * yn;
  float ix = ((gx + 1.0f) * 32.0f - 1.0f) * 0.5f;
  float iy = ((gy + 1.0f) * 32.0f - 1.0f) * 0.5f;
  float x0f = floorf(ix), y0f = floorf(iy);
  float wx = ix - x0f, wy = iy - y0f;
  int x0 = (int)x0f, y0 = (int)y0f;
  int x1 = x0 + 1, y1 = y0 + 1;
  float vx0 = (x0 >= 0 && x0 < 32) ? 1.0f : 0.0f;
  float vx1 = (x1 >= 0 && x1 < 32) ? 1.0f : 0.0f;
  float vy0 = (y0 >= 0 && y0 < 32) ? 1.0f : 0.0f;
  float vy1 = (y1 >= 0 && y1 < 32) ? 1.0f : 0.0f;
  int cx0 = min(max(x0, 0), 31), cx1 = min(max(x1, 0), 31);
  int cy0 = min(max(y0, 0), 31), cy1 = min(max(y1, 0), 31);
  w[0] = (1.0f - wx) * (1.0f - wy) * vx0 * vy0;  p[0] = (cy0 << 5) + cx0;
  w[1] = wx * (1.0f - wy) * vx1 * vy0;           p[1] = (cy0 << 5) + cx1;
  w[2] = (1.0f - wx) * wy * vx0 * vy1;           p[2] = (cy1 << 5) + cx0;
  w[3] = wx * wy * vx1 * vy1;                    p[3] = (cy1 << 5) + cx1;
}

// -------------------------------------------------- fused projection kernel
// grid (32 pblk, 8 b, 2 img) x 512 thr. Now also absorbs prep_k:
// - Wg/Wq staged DIRECTLY from fp32 (RNE convert during LDS store)
// - phase 3 stages W1[:,0:128] from fp32
// - z==1 blocks convert W1 -> W1_h (f16) for main_k (stream-ordered)
// - block (0,0,0) initializes out[] = b2
#define WCH_S 264
#define PS_S  132
#define GN_S  136
__global__ __launch_bounds__(512, 4) void projfused_k(
    const float* __restrict__ gal, const float* __restrict__ qry,
    const float* __restrict__ Wg, const float* __restrict__ Wq,
    const float* __restrict__ W1, const float* __restrict__ b1,
    const float* __restrict__ b2,
    f16* __restrict__ gout, f16* __restrict__ qout,
    float* __restrict__ baseb1, f16* __restrict__ W1_h,
    float* __restrict__ out) {
  __shared__ __align__(16) char LDSU[67584];
  f16*   Wch = (f16*)LDSU;            // [128][264]
  float* ps  = (float*)LDSU;          // [4][32][132]
  f16*   Gn  = (f16*)LDSU;            // [32][136]
  f16*   W1l = (f16*)(LDSU + 8704);   // [128][136]

  int pblk = blockIdx.x, b = blockIdx.y, z = blockIdx.z;
  const float* imgB = (z ? qry : gal) + (size_t)b * CIN * PP;
  const float* Wm32 = z ? Wq : Wg;
  f16* dst = z ? qout : gout;
  int tid = threadIdx.x, lane = tid & 63, wv = tid >> 6;
  int q = lane >> 4, lr = lane & 15;
  int kw = wv & 3, mw = wv >> 2;
  int pw = pblk * 32 + mw * 16;

  if (z == 0 && b == 0 && pblk == 0 && tid < B_ * NA) out[tid] = b2[0];

  f32x4 acc[8];
  #pragma unroll
  for (int t = 0; t < 8; t++) acc[t] = (f32x4){0.f, 0.f, 0.f, 0.f};

  int so = tid >> 2, sseg = (tid & 3) * 64;
  const float* ipb = imgB + (size_t)(kw * 64 + q * 8) * PP + pw + lr;

  float fim[2][16];
  #pragma unroll
  for (int t = 0; t < 16; t++)
    fim[0][t] = ipb[(size_t)((t >> 3) * 32 + (t & 7)) * PP];

  #pragma unroll
  for (int c3 = 0; c3 < 3; c3++) {
    int cc = c3 << 8;
    f16x8 w8[8];                         // stage (fp32 -> f16 RNE) into regs
    #pragma unroll
    for (int j = 0; j < 8; j++) {
      const float* wp = Wm32 + (size_t)so * CIN + cc + sseg + j * 8;
      w8[j] = cvt8_rne(*(const float4*)wp, *(const float4*)(wp + 4));
    }
    if (c3 < 2) {
      #pragma unroll
      for (int t = 0; t < 16; t++)
        fim[(c3 + 1) & 1][t] =
            ipb[(size_t)(((c3 + 1) << 8) + (t >> 3) * 32 + (t & 7)) * PP];
    }
    #pragma unroll
    for (int j = 0; j < 8; j++)
      *(f16x8*)&Wch[so * WCH_S + sseg + j * 8] = w8[j];
    __syncthreads();
    #pragma unroll
    for (int ksi = 0; ksi < 2; ksi++) {
      union { f16x8 v; f16x2 h[4]; } bf;
      const float* fp = &fim[c3 & 1][ksi * 8];
      bf.h[0] = pkrtz(fp[0], fp[1]); bf.h[1] = pkrtz(fp[2], fp[3]);
      bf.h[2] = pkrtz(fp[4], fp[5]); bf.h[3] = pkrtz(fp[6], fp[7]);
      int k0 = kw * 64 + ksi * 32;
      #pragma unroll
      for (int og = 0; og < 8; og++) {
        f16x8 af = *(const f16x8*)&Wch[(og * 16 + lr) * WCH_S + k0 + q * 8];
        acc[og] = MFMA16(af, bf.v, acc[og]);
      }
    }
    __syncthreads();
  }

  // ---- phase 2: psum -> LDS, combine, l2 norm, store
  #pragma unroll
  for (int og = 0; og < 8; og++)
    *(f32x4*)&ps[kw * (32 * PS_S) + (mw * 16 + lr) * PS_S + og * 16 + q * 4] = acc[og];
  __syncthreads();
  int pos = tid >> 4, oo = (tid & 15) * 8;
  f32x4 v0s = (f32x4){0.f,0.f,0.f,0.f}, v1s = (f32x4){0.f,0.f,0.f,0.f};
  #pragma unroll
  for (int k = 0; k < 4; k++) {
    v0s += *(const f32x4*)&ps[k * (32 * PS_S) + pos * PS_S + oo];
    v1s += *(const f32x4*)&ps[k * (32 * PS_S) + pos * PS_S + oo + 4];
  }
  float ss = v0s.x*v0s.x + v0s.y*v0s.y + v0s.z*v0s.z + v0s.w*v0s.w
           + v1s.x*v1s.x + v1s.y*v1s.y + v1s.z*v1s.z + v1s.w*v1s.w;
  ss += __shfl_xor(ss, 1); ss += __shfl_xor(ss, 2);
  ss += __shfl_xor(ss, 4); ss += __shfl_xor(ss, 8);
  float inv = 1.0f / fmaxf(sqrtf(ss), 1e-12f);
  f16x8 gn8;
  gn8[0] = (f16)(v0s.x*inv); gn8[1] = (f16)(v0s.y*inv);
  gn8[2] = (f16)(v0s.z*inv); gn8[3] = (f16)(v0s.w*inv);
  gn8[4] = (f16)(v1s.x*inv); gn8[5] = (f16)(v1s.y*inv);
  gn8[6] = (f16)(v1s.z*inv); gn8[7] = (f16)(v1s.w*inv);
  *(f16x8*)(dst + (size_t)((b << 10) + pblk * 32 + pos) * HID + oo) = gn8;

  if (z == 0) {
    // ---- phase 3 (gallery): baseb1 = W1[:,0:128] @ gn + b1
    __syncthreads();
    *(f16x8*)&Gn[pos * GN_S + oo] = gn8;
    {
      int o = tid >> 2, seg = (tid & 3) * 32;
      #pragma unroll
      for (int j = 0; j < 4; j++) {
        const float* wp = W1 + (size_t)o * 512 + seg + j * 8;
        *(f16x8*)&W1l[o * GN_S + seg + j * 8] =
            cvt8_rne(*(const float4*)wp, *(const float4*)(wp + 4));
      }
    }
    __syncthreads();
    int nw = wv & 3, mw2 = wv >> 2;
    f32x4 acc2[2];
    acc2[0] = (f32x4){0.f,0.f,0.f,0.f}; acc2[1] = (f32x4){0.f,0.f,0.f,0.f};
    #pragma unroll
    for (int ksj = 0; ksj < 4; ksj++) {
      f16x8 bfv = *(const f16x8*)&Gn[(mw2 * 16 + lr) * GN_S + ksj * 32 + q * 8];
      #pragma unroll
      for (int og2 = 0; og2 < 2; og2++) {
        f16x8 af = *(const f16x8*)&W1l[(nw * 32 + og2 * 16 + lr) * GN_S + ksj * 32 + q * 8];
        acc2[og2] = MFMA16(af, bfv, acc2[og2]);
      }
    }
    #pragma unroll
    for (int og2 = 0; og2 < 2; og2++) {
      int o0 = nw * 32 + og2 * 16 + q * 4;
      float4 bb = *(const float4*)(b1 + o0);
      float4 r;
      r.x = acc2[og2][0] + bb.x; r.y = acc2[og2][1] + bb.y;
      r.z = acc2[og2][2] + bb.z; r.w = acc2[og2][3] + bb.w;
      *(float4*)(baseb1 + (size_t)((b << 10) + pblk * 32 + mw2 * 16 + lr) * HID + o0) = r;
    }
  } else {
    // ---- z==1 blocks: convert W1 (fp32) -> W1_h (f16) for main_k.
    // 256 blocks x 128 pairs = 65536 elements, done once per launch.
    if (tid < 128) {
      int e = ((b * 32 + pblk) * 128 + tid) * 2;
      *(f16x2*)(W1_h + e) = pkrtz(0.f, 0.f),      // placate compiler? no-op removed below
      *(f16x2*)(W1_h + e) = (f16x2){(f16)W1[e], (f16)W1[e + 1]};
    }
  }
}

// ------------------------------------------------------------------- main
// grid (32 y, 8 b, 6 ag) x 256 thr. KEY CHANGE vs round 9: the K-loop
// processes TWO angles per W1-fragment load (both X buffers built first),
// halving the per-CU L2 re-read of W1 fragments (~25 us -> ~12 us), which
// round 9 showed to be the co-dominant cost. Register prefetch machinery
// dropped (lower VGPR). LB(256,2): do NOT raise (round 8: spill disaster).
__global__ __launch_bounds__(256, 2) void main_k(
    const f16* __restrict__ g_h, const f16* __restrict__ q_h,
    const float* __restrict__ baseb1, const f16* __restrict__ W1_h,
    const float* __restrict__ W2, const float* __restrict__ angles,
    float* __restrict__ out) {
  __shared__ f16 Xs[2][32 * 392];                 // 50176 B (both in use per phase)
  __shared__ f16 wtab[6][32][4];
  __shared__ unsigned short ptab[6][32][4];
  __shared__ float redl[24];
  int y = blockIdx.x, b = blockIdx.y;
  int tid = threadIdx.x;
  int lane = tid & 63, wv = tid >> 6;
  int q = lane >> 4, lr = lane & 15;
  int nq = wv * 32;

  // ---- corner tables: 6 angles x 32 positions, computed once
  if (tid < 192) {
    int it = tid >> 5, pos = tid & 31;
    float th = angles[blockIdx.z * 6 + it] * 0.017453292519943295f;
    float ct = cosf(th), st = sinf(th);
    float w4[4]; int p4[4];
    rot_corners(ct, st, y, pos, w4, p4);
    f16x4 wh;
    wh[0] = (f16)w4[0]; wh[1] = (f16)w4[1];
    wh[2] = (f16)w4[2]; wh[3] = (f16)w4[3];
    *(f16x4*)&wtab[it][pos][0] = wh;
    us4 ph;
    ph[0] = (unsigned short)p4[0]; ph[1] = (unsigned short)p4[1];
    ph[2] = (unsigned short)p4[2]; ph[3] = (unsigned short)p4[3];
    *(us4*)&ptab[it][pos][0] = ph;
  }

  float w2v[2];
  #pragma unroll
  for (int ni = 0; ni < 2; ni++) w2v[ni] = W2[nq + ni * 16 + lr];

  // ---- base+b1 as MFMA C-init
  f32x4 binit[2][2];
  #pragma unroll
  for (int mi = 0; mi < 2; mi++)
    #pragma unroll
    for (int ni = 0; ni < 2; ni++)
      #pragma unroll
      for (int r = 0; r < 4; r++) {
        int m = mi * 16 + q * 4 + r;
        binit[mi][ni][r] =
            baseb1[(size_t)((b << 10) + (y << 5) + m) * HID + nq + ni * 16 + lr];
      }

  int bx = tid >> 3, ks = tid & 7;
  const f16* qB = q_h + ((size_t)(b << 10)) * HID + ks * 16;
  const f16* gB = g_h + (size_t)((b << 10) + (y << 5) + bx) * HID + ks * 16;
  f16x8 gg[2] = { *(const f16x8*)gB, *(const f16x8*)(gB + 8) };

  const f16* w1p0 = W1_h + (size_t)(nq + lr) * 512 + 128 + q * 8;
  const f16* w1p1 = W1_h + (size_t)(nq + 16 + lr) * 512 + 128 + q * 8;

  __syncthreads();   // wtab/ptab ready

  float spart[6];
  #pragma unroll
  for (int ph2 = 0; ph2 < 3; ph2++) {
    // ---- build X for both angles of this phase
    #pragma unroll
    for (int half = 0; half < 2; half++) {
      int it = ph2 * 2 + half;
      f16* Xb = &Xs[half][0];
      f16x4 wq4 = *(const f16x4*)&wtab[it][bx][0];
      us4 pt = *(const us4*)&ptab[it][bx][0];
      f16x2 wc[4];
      wc[0] = (f16x2){wq4[0], wq4[0]};
      wc[1] = (f16x2){wq4[1], wq4[1]};
      wc[2] = (f16x2){wq4[2], wq4[2]};
      wc[3] = (f16x2){wq4[3], wq4[3]};
      const f16* c0p = qB + (int)pt[0] * HID;
      const f16* c1p = qB + (int)pt[1] * HID;
      const f16* c2p = qB + (int)pt[2] * HID;
      const f16* c3p = qB + (int)pt[3] * HID;
      #pragma unroll
      for (int cg = 0; cg < 2; cg++) {
        int c = ks * 16 + cg * 8;
        union U8 { f16x8 v; f16x2 h[4]; } u0, u1, u2, u3, gv, oq, om, oa;
        u0.v = *(const f16x8*)(c0p + cg * 8);
        u1.v = *(const f16x8*)(c1p + cg * 8);
        u2.v = *(const f16x8*)(c2p + cg * 8);
        u3.v = *(const f16x8*)(c3p + cg * 8);
        gv.v = gg[cg];
        #pragma unroll
        for (int i = 0; i < 4; i++) {
          f16x2 qr = u0.h[i] * wc[0] + u1.h[i] * wc[1]
                   + u2.h[i] * wc[2] + u3.h[i] * wc[3];
          f16x2 mm = gv.h[i] * qr;
          union { f16x2 h; unsigned int uu; } dd;
          dd.h = gv.h[i] - qr;
          dd.uu &= 0x7fff7fffu;
          oq.h[i] = qr; om.h[i] = mm; oa.h[i] = dd.h;
        }
        *(f16x8*)&Xb[bx * 392 + c] = oq.v;
        *(f16x8*)&Xb[bx * 392 + 128 + c] = om.v;
        *(f16x8*)&Xb[bx * 392 + 256 + c] = oa.v;
      }
    }
    __syncthreads();   // X (both angles) visible

    // ---- MFMA: one pass over K, each W1 fragment feeds BOTH angles
    f32x4 aA00 = binit[0][0], aA01 = binit[0][1];
    f32x4 aA10 = binit[1][0], aA11 = binit[1][1];
    f32x4 aB00 = binit[0][0], aB01 = binit[0][1];
    f32x4 aB10 = binit[1][0], aB11 = binit[1][1];
    #pragma unroll
    for (int s = 0; s < 12; s++) {
      f16x8 b0  = *(const f16x8*)(w1p0 + s * 32);
      f16x8 b1v = *(const f16x8*)(w1p1 + s * 32);
      f16x8 fA0 = *(const f16x8*)&Xs[0][(lr) * 392 + s * 32 + q * 8];
      f16x8 fA1 = *(const f16x8*)&Xs[0][(16 + lr) * 392 + s * 32 + q * 8];
      f16x8 fB0 = *(const f16x8*)&Xs[1][(lr) * 392 + s * 32 + q * 8];
      f16x8 fB1 = *(const f16x8*)&Xs[1][(16 + lr) * 392 + s * 32 + q * 8];
      aA00 = MFMA16(fA0, b0, aA00);  aA01 = MFMA16(fA0, b1v, aA01);
      aA10 = MFMA16(fA1, b0, aA10);  aA11 = MFMA16(fA1, b1v, aA11);
      aB00 = MFMA16(fB0, b0, aB00);  aB01 = MFMA16(fB0, b1v, aB01);
      aB10 = MFMA16(fB1, b0, aB10);  aB11 = MFMA16(fB1, b1v, aB11);
    }

    // ---- epilogue for both angles
    float svA = 0.f, svB = 0.f;
    #pragma unroll
    for (int r = 0; r < 4; r++) {
      svA = fmaf(w2v[0], fmaxf(aA00[r], 0.f), svA);
      svA = fmaf(w2v[1], fmaxf(aA01[r], 0.f), svA);
      svA = fmaf(w2v[0], fmaxf(aA10[r], 0.f), svA);
      svA = fmaf(w2v[1], fmaxf(aA11[r], 0.f), svA);
      svB = fmaf(w2v[0], fmaxf(aB00[r], 0.f), svB);
      svB = fmaf(w2v[1], fmaxf(aB01[r], 0.f), svB);
      svB = fmaf(w2v[0], fmaxf(aB10[r], 0.f), svB);
      svB = fmaf(w2v[1], fmaxf(aB11[r], 0.f), svB);
    }
    spart[ph2 * 2]     = svA;
    spart[ph2 * 2 + 1] = svB;
    __syncthreads();   // WAR: X rebuild next phase
  }

  // ---- one reduction + atomic for all 6 angles
  #pragma unroll
  for (int it = 0; it < 6; it++) {
    float v = spart[it];
    #pragma unroll
    for (int off = 32; off > 0; off >>= 1) v += __shfl_down(v, off, 64);
    if (lane == 0) redl[wv * 6 + it] = v;
  }
  __syncthreads();
  if (tid < 6) {
    float tot = redl[tid] + redl[6 + tid] + redl[12 + tid] + redl[18 + tid];
    atomicAdd(&out[b * NA + blockIdx.z * 6 + tid], tot * (1.0f / 1024.0f));
  }
}

// --------------------------------------------------------------------- launch
extern "C" void kernel_launch(void* const* d_in, const int* in_sizes, int n_in,
                              void* d_out, int out_size, void* d_ws, size_t ws_size,
                              hipStream_t stream) {
  const float* gal = (const float*)d_in[0];
  const float* qry = (const float*)d_in[1];
  const float* Wg  = (const float*)d_in[2];
  const float* Wq  = (const float*)d_in[3];
  const float* W1  = (const float*)d_in[4];
  const float* b1  = (const float*)d_in[5];
  const float* W2  = (const float*)d_in[6];
  const float* b2  = (const float*)d_in[7];
  const float* ang = (const float*)d_in[8];
  float* out = (float*)d_out;
  char* ws = (char*)d_ws;
  f16*   g_h    = (f16*)ws;                              // 2 MB
  f16*   q_h    = (f16*)(ws + (2u << 20));               // 2 MB
  float* baseb1 = (float*)(ws + (4u << 20));             // 4 MB
  f16*   W1_h   = (f16*)(ws + (8u << 20));               // 128 KB

  hipLaunchKernelGGL(projfused_k, dim3(32, 8, 2), dim3(512), 0, stream,
                     gal, qry, Wg, Wq, W1, b1, b2, g_h, q_h, baseb1, W1_h, out);
  hipLaunchKernelGGL(main_k, dim3(32, 8, 6), dim3(256), 0, stream,
                     g_h, q_h, baseb1, W1_h, W2, ang, out);
}